// Round 1
// 309.991 us; speedup vs baseline: 1.0170x; 1.0170x over previous
//
#include <hip/hip_runtime.h>
#include <math.h>

// Problem constants (match reference)
#define BB 32
#define NN 64
#define CC 8
#define HH 64
#define PP 16
#define LL 8

// Fully fused: one block per batch b. 16 waves/block, one wave per path p.
// Lane j owns feature dim j. Gather+mean-pool in registers (edge list fully
// unrolled + predicated so the node array stays in VGPRs, not scratch),
// broadcast inp[k] via shuffle, 128-wide MLP, shuffle-reduce the W2 dot.
// Scores pass through 16 floats of LDS; wave 0 (lanes 0..15) does the
// masked softmax / log-softmax / entropy and writes all outputs.
// ZERO d_ws usage, single dispatch.
__global__ __launch_bounds__(1024) void fused_kernel(
    const float* __restrict__ ef,            // (B,N,N,C,H)
    const float* __restrict__ ge,            // (B,H)
    const int*   __restrict__ sc,            // (B,)
    const int*   __restrict__ paths,         // (B,P,L)
    const int*   __restrict__ plen,          // (B,P)
    const int*   __restrict__ pmask,         // (B,P) bool widened to int32
    const float* __restrict__ W1,            // (128,128) row-major
    const float* __restrict__ b1,            // (128,)
    const float* __restrict__ W2,            // (128,)
    const float* __restrict__ b2,            // (1,)
    float* __restrict__ out)                 // probs(512) | log_probs(512) | ent(32)
{
    __shared__ float sl[PP];

    const int b    = blockIdx.x;
    const int wid  = threadIdx.x >> 6;       // path index 0..15
    const int lane = threadIdx.x & 63;       // feature dim

    const int c = sc[b];

    // ---- gather + mean pool (register-resident, lane = feature dim) ----
    const int* pp = paths + (b * PP + wid) * LL;
    int cnt = plen[b * PP + wid] - 1;
    cnt = (cnt < 1) ? 1 : (cnt > LL - 1 ? LL - 1 : cnt);

    // 32B-aligned vector load of the 8 path nodes; static indexing after
    // full unroll keeps nd[] in VGPRs (no scratch).
    const int4 q0 = *reinterpret_cast<const int4*>(pp);
    const int4 q1 = *reinterpret_cast<const int4*>(pp + 4);
    const int nd[LL] = {q0.x, q0.y, q0.z, q0.w, q1.x, q1.y, q1.z, q1.w};

    float s = 0.0f;
    #pragma unroll
    for (int e = 0; e < LL - 1; ++e) {
        if (e < cnt) {
            const int u = nd[e];
            const int v = nd[e + 1];
            s += ef[(((b * NN + u) * NN + v) * CC + c) * HH + lane];
        }
    }
    const float pf = s / (float)cnt;          // path_feat[lane]
    const float gv = ge[b * HH + lane];       // graph_embedding[lane]

    // ---- MLP: h = relu(inp @ W1 + b1); score = h @ W2 + b2 ----
    float h1 = b1[lane];
    float h2 = b1[64 + lane];
    #pragma unroll 8
    for (int k = 0; k < 64; ++k) {
        const float a = __shfl(pf, k, 64);    // broadcast inp[k]
        h1 += a * W1[k * 128 + lane];         // coalesced, L1-resident
        h2 += a * W1[k * 128 + 64 + lane];
    }
    #pragma unroll 8
    for (int k = 0; k < 64; ++k) {
        const float a = __shfl(gv, k, 64);    // broadcast inp[64+k]
        h1 += a * W1[(64 + k) * 128 + lane];
        h2 += a * W1[(64 + k) * 128 + 64 + lane];
    }
    h1 = fmaxf(h1, 0.0f);
    h2 = fmaxf(h2, 0.0f);

    float cs = h1 * W2[lane] + h2 * W2[64 + lane];
    #pragma unroll
    for (int off = 32; off >= 1; off >>= 1)
        cs += __shfl_down(cs, off, 64);
    if (lane == 0) sl[wid] = cs + b2[0];

    __syncthreads();

    // ---- masked softmax / log-softmax / entropy: wave 0, lanes 0..15 ----
    if (threadIdx.x < PP) {
        const int p = threadIdx.x;
        const bool m = pmask[b * PP + p] != 0;
        const float sv = m ? sl[p] : -INFINITY;

        float mx = sv;
        #pragma unroll
        for (int off = 8; off >= 1; off >>= 1)
            mx = fmaxf(mx, __shfl_xor(mx, off, 64));   // partners stay in 0..15

        const float e = m ? expf(sv - mx) : 0.0f;
        float se = e;
        #pragma unroll
        for (int off = 8; off >= 1; off >>= 1)
            se += __shfl_xor(se, off, 64);

        const float prob = e / se;
        const float lse  = logf(se);
        const float lp   = (sv - mx) - lse;            // -inf where masked (matches ref)
        const float lps  = m ? lp : 0.0f;

        float ent = -prob * lps;
        #pragma unroll
        for (int off = 8; off >= 1; off >>= 1)
            ent += __shfl_xor(ent, off, 64);

        out[b * PP + p]           = prob;              // action_probs
        out[BB * PP + b * PP + p] = lp;                // log_probs
        if (p == 0) out[2 * BB * PP + b] = ent;        // entropy
    }
}

extern "C" void kernel_launch(void* const* d_in, const int* in_sizes, int n_in,
                              void* d_out, int out_size, void* d_ws, size_t ws_size,
                              hipStream_t stream) {
    const float* ef    = (const float*)d_in[0];
    const float* ge    = (const float*)d_in[1];
    const int*   sc    = (const int*)d_in[2];
    const int*   paths = (const int*)d_in[3];
    const int*   plen  = (const int*)d_in[4];
    const int*   pmask = (const int*)d_in[5];
    const float* W1    = (const float*)d_in[6];
    const float* b1    = (const float*)d_in[7];
    const float* W2    = (const float*)d_in[8];
    const float* b2    = (const float*)d_in[9];
    float*       out   = (float*)d_out;

    (void)d_ws; (void)ws_size;  // deliberately unused: zero workspace traffic

    // One block per batch, one wave per path: 32 x 1024 threads, 1 dispatch.
    fused_kernel<<<BB, PP * 64, 0, stream>>>(
        ef, ge, sc, paths, plen, pmask, W1, b1, W2, b2, out);
}